// Round 8
// baseline (357.843 us; speedup 1.0000x reference)
//
#include <hip/hip_runtime.h>
#include <hip/hip_bf16.h>

// ---------------------------------------------------------------------------
// PGAConjugateLinear as bf16 MFMA GEMM + bias.
//   out[b, n=o*3+p] = sum_{k=i*3+r} A[b][k] * Bw[n][k]  +  bias[n]
// GEMM: M=4096, N=1536, K=1536. Tile 64x128, BK=64, grid 768 = 3 blocks/CU.
// 8 waves = 2m x 2n x 2k: each wave owns a 32x64 output tile over HALF of
// each BK step (k-split) -> fragment reads 6/step/wave instead of 8
// (FLOP per LDS byte 16 -> 21.3; the R5 structure was LDS-read-bound).
// k-partial accumulators merged in a 32 KB LDS epilogue reduction.
// Pipeline: R5's proven stage-early + __syncthreads double buffer.
// LDS stripe-transpose layout slot=(row>>3)*64+g*8+(row&7): 0 bank conflicts
// (verified R6/R7) and linear global_load_lds dest (slot = staging tid).
// ---------------------------------------------------------------------------

#define B_DIM 4096
#define I_DIM 512
#define O_DIM 512
#define N_DIM (O_DIM * 3)   // 1536
#define K_DIM (I_DIM * 3)   // 1536
#define BK 64
#define NT (K_DIM / BK)     // 24 K-steps

typedef __attribute__((ext_vector_type(8))) short bf16x8;
typedef __attribute__((ext_vector_type(4))) float f32x4;

__device__ __forceinline__ unsigned short f2bf(float f) {
    unsigned u = __float_as_uint(f);
    unsigned r = (u + 0x7fffu + ((u >> 16) & 1u)) >> 16;  // RNE
    return (unsigned short)r;
}

__device__ __forceinline__ void gload_lds16(const void* g, void* l) {
    __builtin_amdgcn_global_load_lds(
        (const __attribute__((address_space(1))) unsigned*)g,
        (__attribute__((address_space(3))) unsigned*)l, 16, 0, 0);
}

// Cayley table for Cl(3,0,1), metric [0,1,1,1], reference blade order.
struct Cayley {
    float M[16][16][16];
    float rev[16];
    constexpr Cayley() : M{}, rev{} {
        const unsigned masks[16] = {0u, 1u, 2u, 4u, 8u, 3u, 5u, 9u, 6u, 10u,
                                    12u, 7u, 11u, 13u, 14u, 15u};
        int idx_of[16] = {};
        for (int i = 0; i < 16; ++i) idx_of[masks[i]] = i;
        const int metric[4] = {0, 1, 1, 1};
        for (int i = 0; i < 16; ++i) {
            unsigned a = masks[i];
            for (int j = 0; j < 16; ++j) {
                unsigned b = masks[j];
                int swaps = 0;
                for (int jb = 0; jb < 4; ++jb)
                    if ((b >> jb) & 1u)
                        for (int ia = jb + 1; ia < 4; ++ia)
                            if ((a >> ia) & 1u) ++swaps;
                int sign = (swaps & 1) ? -1 : 1;
                unsigned common = a & b;
                for (int g = 0; g < 4; ++g)
                    if ((common >> g) & 1u) sign *= metric[g];
                if (sign != 0) M[i][j][idx_of[a ^ b]] += (float)sign;
            }
            int grade = 0;
            for (int g = 0; g < 4; ++g) grade += (int)((a >> g) & 1u);
            rev[i] = ((grade * (grade - 1) / 2) % 2) ? -1.f : 1.f;
        }
    }
};
constexpr Cayley CAY{};

// ---------------------------------------------------------------------------
// prep: fused pack_x (blocks 0..1535) + build_w/bias (blocks 1536..2047).
// ---------------------------------------------------------------------------
__global__ __launch_bounds__(512) void prep(const float* __restrict__ x,
                                            const float* __restrict__ weight,
                                            const float* __restrict__ action,
                                            const float* __restrict__ e0,
                                            unsigned short* __restrict__ A,
                                            unsigned short* __restrict__ Bw,
                                            float* __restrict__ bias) {
    const int bid = blockIdx.x;
    const int tid = threadIdx.x;

    if (bid < 1536) {
        // ---- pack: A = bf16(x), flat cast (k=i*3+r is exactly x's layout)
        const size_t t = (size_t)bid * 512 + tid;
        const float4* xp = (const float4*)(x + t * 8);
        const float4 v0 = xp[0], v1 = xp[1];
        const float xs[8] = {v0.x, v0.y, v0.z, v0.w, v1.x, v1.y, v1.z, v1.w};
        unsigned short ov[8];
#pragma unroll
        for (int q = 0; q < 8; ++q) ov[q] = f2bf(xs[q]);
        *(uint4*)(A + t * 8) = *(const uint4*)ov;   // 16B store
        return;
    }

    // ---- build: one block per o, one thread per i.
    const int o = bid - 1536;
    const int i = tid;
    const int t = o * I_DIM + i;
    const int wave = tid >> 6, lane = tid & 63;
    __shared__ float red[8][3];

    constexpr int AB[8] = {0, 5, 6, 7, 8, 9, 10, 15};
    constexpr int PB[3] = {11, 12, 13};
    constexpr int RB[4] = {11, 12, 13, 14};

    float a[8];
    const float* ap = action + (size_t)t * 8;
#pragma unroll
    for (int j = 0; j < 8; ++j) a[j] = ap[j];

    float kv[16], kr[16];
#pragma unroll
    for (int j = 0; j < 16; ++j) { kv[j] = 0.f; kr[j] = 0.f; }
#pragma unroll
    for (int j = 0; j < 8; ++j) {
        kv[AB[j]] = a[j];
        kr[AB[j]] = a[j] * CAY.rev[AB[j]];
    }

    float Am[3][16];
#pragma unroll
    for (int pp = 0; pp < 3; ++pp)
#pragma unroll
        for (int q = 0; q < 16; ++q) {
            float s = 0.f;
#pragma unroll
            for (int tt = 0; tt < 16; ++tt) s += CAY.M[q][PB[pp]][tt] * kr[tt];
            Am[pp][q] = s;
        }

    float Bm[16][4];
#pragma unroll
    for (int q = 0; q < 16; ++q)
#pragma unroll
        for (int rr = 0; rr < 4; ++rr) {
            float s = 0.f;
#pragma unroll
            for (int m = 0; m < 16; ++m) s += CAY.M[m][q][RB[rr]] * kv[m];
            Bm[q][rr] = s;
        }

    const float w = weight[t];
    const float e0i = e0[i];
    float sb[3];
#pragma unroll
    for (int pp = 0; pp < 3; ++pp) {
        float r0 = 0.f, r1 = 0.f, r2 = 0.f, r3 = 0.f;
#pragma unroll
        for (int q = 0; q < 16; ++q) {
            r0 += Am[pp][q] * Bm[q][0];
            r1 += Am[pp][q] * Bm[q][1];
            r2 += Am[pp][q] * Bm[q][2];
            r3 += Am[pp][q] * Bm[q][3];
        }
        unsigned short* bp = Bw + (size_t)(o * 3 + pp) * K_DIM + i * 3;
        bp[0] = f2bf(w * r0);
        bp[1] = f2bf(w * r1);
        bp[2] = f2bf(w * r2);
        sb[pp] = w * r3 * e0i;
    }

#pragma unroll
    for (int off = 32; off; off >>= 1) {
#pragma unroll
        for (int pp = 0; pp < 3; ++pp) sb[pp] += __shfl_down(sb[pp], off, 64);
    }
    if (lane == 0) {
#pragma unroll
        for (int pp = 0; pp < 3; ++pp) red[wave][pp] = sb[pp];
    }
    __syncthreads();
    if (tid == 0) {
#pragma unroll
        for (int pp = 0; pp < 3; ++pp) {
            float s = 0.f;
#pragma unroll
            for (int wv = 0; wv < 8; ++wv) s += red[wv][pp];
            bias[o * 3 + pp] = s;
        }
    }
}

// ---------------------------------------------------------------------------
// gemm: C[m][n] = sum_k A[m][k]*Bw[n][k] + bias[n].
// Waves: wr=wave>>2 (m-half), wc=(wave>>1)&1 (n-half), kk=wave&1 (k-half).
// ---------------------------------------------------------------------------
__global__ __launch_bounds__(512, 6) void gemm_bf16(
        const unsigned short* __restrict__ A,
        const unsigned short* __restrict__ Bw,
        const float* __restrict__ bias,
        float* __restrict__ C) {
    __shared__ unsigned short LDS[24576];          // 48 KB
    unsigned short* const As0 = LDS;               // 4096 shorts (8 KB)
    unsigned short* const Bs0 = LDS + 4096;        // 8192 shorts (16 KB)
    unsigned short* const As1 = LDS + 12288;       // 4096 shorts
    unsigned short* const Bs1 = LDS + 16384;       // 8192 shorts

    const int tid = threadIdx.x;
    const int wave = tid >> 6, lane = tid & 63;

    // XCD-chunked bijective swizzle (768 % 8 == 0), m-tile-major in chunk.
    const int bid = blockIdx.x;
    const int swz = (bid & 7) * 96 + (bid >> 3);
    const int mt = swz / 12, nt = swz - mt * 12;
    const int m0 = mt * 64, n0 = nt * 128;
    const int wr = wave >> 2, wc = (wave >> 1) & 1, kk = wave & 1;

    // staging (R7-proven): LDS slot s holds global (row=(s>>6)*8+(s&7),
    // colseg g=(s>>3)&7); thread stages A seg tid + B segs tid, tid+512.
    const int aRow = ((tid >> 6) * 8) + (tid & 7);
    const int aG = (tid >> 3) & 7;
    const unsigned short* aSrc = A + (size_t)(m0 + aRow) * K_DIM + aG * 8;
    const unsigned short* bSrc0 = Bw + (size_t)(n0 + aRow) * K_DIM + aG * 8;
    const int b1s = tid + 512;
    const unsigned short* bSrc1 =
        Bw + (size_t)(n0 + ((b1s >> 6) * 8) + (b1s & 7)) * K_DIM + ((b1s >> 3) & 7) * 8;

    // fragment read offsets (shorts): slot(r,g)*8 with g = kk*4 + (lane>>4)
    const int frow = lane & 15;
    const int gk = kk * 4 + (lane >> 4);
    int aro[2], bro[4];
#pragma unroll
    for (int mi = 0; mi < 2; ++mi) {
        const int r = wr * 32 + mi * 16 + frow;
        aro[mi] = (((r >> 3) * 64) + gk * 8 + (r & 7)) * 8;
    }
#pragma unroll
    for (int ni = 0; ni < 4; ++ni) {
        const int r = wc * 64 + ni * 16 + frow;
        bro[ni] = (((r >> 3) * 64) + gk * 8 + (r & 7)) * 8;
    }

    f32x4 acc[2][4] = {};   // k-partial: this wave's half-K contribution

#define STAGE(AS, BS, T)                                        \
    do {                                                        \
        gload_lds16(aSrc + (size_t)(T) * BK, (AS) + tid * 8);   \
        gload_lds16(bSrc0 + (size_t)(T) * BK, (BS) + tid * 8);  \
        gload_lds16(bSrc1 + (size_t)(T) * BK, (BS) + b1s * 8);  \
    } while (0)

#define COMPUTE(AS, BS)                                                   \
    do {                                                                  \
        bf16x8 af[2], bv[4];                                              \
        _Pragma("unroll")                                                 \
        for (int mi = 0; mi < 2; ++mi)                                    \
            af[mi] = *(const bf16x8*)&(AS)[aro[mi]];                      \
        _Pragma("unroll")                                                 \
        for (int ni = 0; ni < 4; ++ni)                                    \
            bv[ni] = *(const bf16x8*)&(BS)[bro[ni]];                      \
        _Pragma("unroll")                                                 \
        for (int mi = 0; mi < 2; ++mi)                                    \
            _Pragma("unroll")                                             \
            for (int ni = 0; ni < 4; ++ni)                                \
                acc[mi][ni] = __builtin_amdgcn_mfma_f32_16x16x32_bf16(    \
                    af[mi], bv[ni], acc[mi][ni], 0, 0, 0);                \
    } while (0)

    STAGE(As0, Bs0, 0);
    __syncthreads();                       // buf0 ready

#pragma unroll 1
    for (int t = 0; t < NT - 2; t += 2) {
        STAGE(As1, Bs1, t + 1);            // issue next-tile loads FIRST
        COMPUTE(As0, Bs0);                 // MFMA + co-resident waves hide them
        __syncthreads();
        STAGE(As0, Bs0, t + 2);
        COMPUTE(As1, Bs1);
        __syncthreads();
    }
    STAGE(As1, Bs1, NT - 1);
    COMPUTE(As0, Bs0);
    __syncthreads();
    COMPUTE(As1, Bs1);

#undef STAGE
#undef COMPUTE

    // ---- epilogue: merge the two k-halves of each (wr,wc) pair via LDS.
    // Wave kk keeps mi==kk rows for itself, ships mi==1-kk to its partner.
    __syncthreads();                       // all COMPUTE reads of LDS done
    float* red = (float*)LDS;              // 32 KB of the 48 used
    const int p = wave >> 1;               // pair id 0..3 (wr*2+wc)
#pragma unroll
    for (int ni = 0; ni < 4; ++ni) {
        const f32x4 send = (kk == 0) ? acc[1][ni] : acc[0][ni];
        *(f32x4*)&red[p * 2048 + kk * 1024 + ni * 256 + lane * 4] = send;
    }
    __syncthreads();

    // C/D fragment layout: col = lane&15, row = (lane>>4)*4 + j.
    const int crow = (lane >> 4) * 4;
    const int ccol = lane & 15;
#pragma unroll
    for (int ni = 0; ni < 4; ++ni) {
        const f32x4 own = (kk == 0) ? acc[0][ni] : acc[1][ni];
        const f32x4 other =
            *(const f32x4*)&red[p * 2048 + (1 - kk) * 1024 + ni * 256 + lane * 4];
        const int n = n0 + wc * 64 + ni * 16 + ccol;
        const float bv = bias[n];
        float* cp = C + (size_t)(m0 + wr * 32 + kk * 16 + crow) * N_DIM + n;
#pragma unroll
        for (int j = 0; j < 4; ++j)
            cp[(size_t)j * N_DIM] = own[j] + other[j] + bv;
    }
}

// ---------------------------------------------------------------------------
extern "C" void kernel_launch(void* const* d_in, const int* in_sizes, int n_in,
                              void* d_out, int out_size, void* d_ws, size_t ws_size,
                              hipStream_t stream) {
    const float* x      = (const float*)d_in[0];  // (4096, 512, 3)
    const float* weight = (const float*)d_in[1];  // (512, 512)
    const float* action = (const float*)d_in[2];  // (512, 512, 8)
    const float* e0     = (const float*)d_in[3];  // (512, 1)
    float* out = (float*)d_out;                   // (4096, 512, 3)

    unsigned short* Bw = (unsigned short*)d_ws;                 // 4.7 MB
    unsigned short* Ap = Bw + (size_t)N_DIM * K_DIM;            // 12.6 MB
    float* bias = (float*)(Ap + (size_t)B_DIM * K_DIM);         // 1536 f32

    hipLaunchKernelGGL(prep, dim3(2048), dim3(512), 0, stream,
                       x, weight, action, e0, Ap, Bw, bias);
    hipLaunchKernelGGL(gemm_bf16, dim3(768), dim3(512), 0, stream,
                       Ap, Bw, bias, out);
}

// Round 9
// 59.451 us; speedup vs baseline: 6.0191x; 6.0191x over previous
//
#include <hip/hip_runtime.h>
#include <hip/hip_bf16.h>

// ---------------------------------------------------------------------------
// PGAConjugateLinear as bf16 MFMA GEMM + bias.
//   out[b, n=o*3+p] = sum_{k=i*3+r} A[b][k] * Bw[n][k]  +  bias[n]
// GEMM: M=4096, N=1536, K=1536. Tile 128x96, BK=64, 4 waves (2x2) of 64x48
// -> FLOP/LDS-byte = 27.4 (vs 16 in the 32x32-wave R5 structure; LDS-read
// floor 23 -> 13.5 us). Grid 32x16 = 512 = exactly 2 blocks/CU (LDS 56 KB
// dbuf x2 = 112 KB). acc[4][3]=48 VGPR; launch_bounds(256,2) -> no VGPR cap
// below 256, no spill (R8's failure mode, diagnosed via WRITE_SIZE=1.16GB).
// Pipeline: R5-proven stage-early + __syncthreads double buffer.
// LDS stripe-transpose layout slot=(row>>3)*64+g*8+(row&7): 0 bank conflicts
// (verified R6/R7) and linear global_load_lds dest (slot = staging index).
// ---------------------------------------------------------------------------

#define B_DIM 4096
#define I_DIM 512
#define O_DIM 512
#define N_DIM (O_DIM * 3)   // 1536
#define K_DIM (I_DIM * 3)   // 1536
#define BK 64
#define NT (K_DIM / BK)     // 24 K-steps

typedef __attribute__((ext_vector_type(8))) short bf16x8;
typedef __attribute__((ext_vector_type(4))) float f32x4;

__device__ __forceinline__ unsigned short f2bf(float f) {
    unsigned u = __float_as_uint(f);
    unsigned r = (u + 0x7fffu + ((u >> 16) & 1u)) >> 16;  // RNE
    return (unsigned short)r;
}

__device__ __forceinline__ void gload_lds16(const void* g, void* l) {
    __builtin_amdgcn_global_load_lds(
        (const __attribute__((address_space(1))) unsigned*)g,
        (__attribute__((address_space(3))) unsigned*)l, 16, 0, 0);
}

// Cayley table for Cl(3,0,1), metric [0,1,1,1], reference blade order.
struct Cayley {
    float M[16][16][16];
    float rev[16];
    constexpr Cayley() : M{}, rev{} {
        const unsigned masks[16] = {0u, 1u, 2u, 4u, 8u, 3u, 5u, 9u, 6u, 10u,
                                    12u, 7u, 11u, 13u, 14u, 15u};
        int idx_of[16] = {};
        for (int i = 0; i < 16; ++i) idx_of[masks[i]] = i;
        const int metric[4] = {0, 1, 1, 1};
        for (int i = 0; i < 16; ++i) {
            unsigned a = masks[i];
            for (int j = 0; j < 16; ++j) {
                unsigned b = masks[j];
                int swaps = 0;
                for (int jb = 0; jb < 4; ++jb)
                    if ((b >> jb) & 1u)
                        for (int ia = jb + 1; ia < 4; ++ia)
                            if ((a >> ia) & 1u) ++swaps;
                int sign = (swaps & 1) ? -1 : 1;
                unsigned common = a & b;
                for (int g = 0; g < 4; ++g)
                    if ((common >> g) & 1u) sign *= metric[g];
                if (sign != 0) M[i][j][idx_of[a ^ b]] += (float)sign;
            }
            int grade = 0;
            for (int g = 0; g < 4; ++g) grade += (int)((a >> g) & 1u);
            rev[i] = ((grade * (grade - 1) / 2) % 2) ? -1.f : 1.f;
        }
    }
};
constexpr Cayley CAY{};

// ---------------------------------------------------------------------------
// prep: fused pack_x (blocks 0..1535) + build_w/bias (blocks 1536..2047).
// ---------------------------------------------------------------------------
__global__ __launch_bounds__(512) void prep(const float* __restrict__ x,
                                            const float* __restrict__ weight,
                                            const float* __restrict__ action,
                                            const float* __restrict__ e0,
                                            unsigned short* __restrict__ A,
                                            unsigned short* __restrict__ Bw,
                                            float* __restrict__ bias) {
    const int bid = blockIdx.x;
    const int tid = threadIdx.x;

    if (bid < 1536) {
        // ---- pack: A = bf16(x), flat cast (k=i*3+r is exactly x's layout)
        const size_t t = (size_t)bid * 512 + tid;
        const float4* xp = (const float4*)(x + t * 8);
        const float4 v0 = xp[0], v1 = xp[1];
        const float xs[8] = {v0.x, v0.y, v0.z, v0.w, v1.x, v1.y, v1.z, v1.w};
        unsigned short ov[8];
#pragma unroll
        for (int q = 0; q < 8; ++q) ov[q] = f2bf(xs[q]);
        *(uint4*)(A + t * 8) = *(const uint4*)ov;   // 16B store
        return;
    }

    // ---- build: one block per o, one thread per i.
    const int o = bid - 1536;
    const int i = tid;
    const int t = o * I_DIM + i;
    const int wave = tid >> 6, lane = tid & 63;
    __shared__ float red[8][3];

    constexpr int AB[8] = {0, 5, 6, 7, 8, 9, 10, 15};
    constexpr int PB[3] = {11, 12, 13};
    constexpr int RB[4] = {11, 12, 13, 14};

    float a[8];
    const float* ap = action + (size_t)t * 8;
#pragma unroll
    for (int j = 0; j < 8; ++j) a[j] = ap[j];

    float kv[16], kr[16];
#pragma unroll
    for (int j = 0; j < 16; ++j) { kv[j] = 0.f; kr[j] = 0.f; }
#pragma unroll
    for (int j = 0; j < 8; ++j) {
        kv[AB[j]] = a[j];
        kr[AB[j]] = a[j] * CAY.rev[AB[j]];
    }

    float Am[3][16];
#pragma unroll
    for (int pp = 0; pp < 3; ++pp)
#pragma unroll
        for (int q = 0; q < 16; ++q) {
            float s = 0.f;
#pragma unroll
            for (int tt = 0; tt < 16; ++tt) s += CAY.M[q][PB[pp]][tt] * kr[tt];
            Am[pp][q] = s;
        }

    float Bm[16][4];
#pragma unroll
    for (int q = 0; q < 16; ++q)
#pragma unroll
        for (int rr = 0; rr < 4; ++rr) {
            float s = 0.f;
#pragma unroll
            for (int m = 0; m < 16; ++m) s += CAY.M[m][q][RB[rr]] * kv[m];
            Bm[q][rr] = s;
        }

    const float w = weight[t];
    const float e0i = e0[i];
    float sb[3];
#pragma unroll
    for (int pp = 0; pp < 3; ++pp) {
        float r0 = 0.f, r1 = 0.f, r2 = 0.f, r3 = 0.f;
#pragma unroll
        for (int q = 0; q < 16; ++q) {
            r0 += Am[pp][q] * Bm[q][0];
            r1 += Am[pp][q] * Bm[q][1];
            r2 += Am[pp][q] * Bm[q][2];
            r3 += Am[pp][q] * Bm[q][3];
        }
        unsigned short* bp = Bw + (size_t)(o * 3 + pp) * K_DIM + i * 3;
        bp[0] = f2bf(w * r0);
        bp[1] = f2bf(w * r1);
        bp[2] = f2bf(w * r2);
        sb[pp] = w * r3 * e0i;
    }

#pragma unroll
    for (int off = 32; off; off >>= 1) {
#pragma unroll
        for (int pp = 0; pp < 3; ++pp) sb[pp] += __shfl_down(sb[pp], off, 64);
    }
    if (lane == 0) {
#pragma unroll
        for (int pp = 0; pp < 3; ++pp) red[wave][pp] = sb[pp];
    }
    __syncthreads();
    if (tid == 0) {
#pragma unroll
        for (int pp = 0; pp < 3; ++pp) {
            float s = 0.f;
#pragma unroll
            for (int wv = 0; wv < 8; ++wv) s += red[wv][pp];
            bias[o * 3 + pp] = s;
        }
    }
}

// ---------------------------------------------------------------------------
// gemm: C[m][n] = sum_k A[m][k]*Bw[n][k] + bias[n].
// 4 waves (2x2): wr = wave>>1 -> m-offset wr*64; wc = wave&1 -> n-offset wc*48.
// ---------------------------------------------------------------------------
__global__ __launch_bounds__(256, 2) void gemm_bf16(
        const unsigned short* __restrict__ A,
        const unsigned short* __restrict__ Bw,
        const float* __restrict__ bias,
        float* __restrict__ C) {
    __shared__ unsigned short As0[128 * 64], As1[128 * 64];  // 16 KB each
    __shared__ unsigned short Bs0[96 * 64], Bs1[96 * 64];    // 12 KB each

    const int tid = threadIdx.x;
    const int wave = tid >> 6, lane = tid & 63;

    // XCD-chunked bijective swizzle (512 % 8 == 0), m-tile-major in chunk.
    const int bid = blockIdx.x;
    const int swz = (bid & 7) * 64 + (bid >> 3);
    const int mt = swz >> 4, nt = swz & 15;
    const int m0 = mt * 128, n0 = nt * 96;
    const int wr = wave >> 1, wc = wave & 1;

    // staging: LDS slot s (16B) holds global (row=(s>>6)*8+(s&7), g=(s>>3)&7).
    // Thread stages A slots tid+q*256 (q=0..3; +256 -> row+32, same g) and
    // B slots tid+q*256 (q=0..2). 7 loads/thread, uniform.
    const int sRow = ((tid >> 6) * 8) + (tid & 7);
    const int sG = (tid >> 3) & 7;
    const unsigned short* aSrc = A + (size_t)(m0 + sRow) * K_DIM + sG * 8;
    const unsigned short* bSrc = Bw + (size_t)(n0 + sRow) * K_DIM + sG * 8;

    // fragment read offsets (shorts): slot(r,g)*8, g = kh*4 + (lane>>4)
    const int frow = lane & 15;
    const int gl = lane >> 4;
    int aro[2][4], bro[2][3];
#pragma unroll
    for (int kh = 0; kh < 2; ++kh) {
        const int g = kh * 4 + gl;
#pragma unroll
        for (int mi = 0; mi < 4; ++mi) {
            const int r = wr * 64 + mi * 16 + frow;
            aro[kh][mi] = (((r >> 3) * 64) + g * 8 + (r & 7)) * 8;
        }
#pragma unroll
        for (int ni = 0; ni < 3; ++ni) {
            const int r = wc * 48 + ni * 16 + frow;
            bro[kh][ni] = (((r >> 3) * 64) + g * 8 + (r & 7)) * 8;
        }
    }

    f32x4 acc[4][3] = {};

#define STAGE(AS, BS, T)                                                      \
    do {                                                                      \
        _Pragma("unroll")                                                     \
        for (int q = 0; q < 4; ++q)                                           \
            gload_lds16(aSrc + (size_t)(T) * BK + q * 32 * K_DIM,             \
                        (AS) + (tid + q * 256) * 8);                          \
        _Pragma("unroll")                                                     \
        for (int q = 0; q < 3; ++q)                                           \
            gload_lds16(bSrc + (size_t)(T) * BK + q * 32 * K_DIM,             \
                        (BS) + (tid + q * 256) * 8);                          \
    } while (0)

#define COMPUTE(AS, BS)                                                       \
    do {                                                                      \
        _Pragma("unroll")                                                     \
        for (int kh = 0; kh < 2; ++kh) {                                      \
            bf16x8 af[4], bv[3];                                              \
            _Pragma("unroll")                                                 \
            for (int mi = 0; mi < 4; ++mi)                                    \
                af[mi] = *(const bf16x8*)&(AS)[aro[kh][mi]];                  \
            _Pragma("unroll")                                                 \
            for (int ni = 0; ni < 3; ++ni)                                    \
                bv[ni] = *(const bf16x8*)&(BS)[bro[kh][ni]];                  \
            _Pragma("unroll")                                                 \
            for (int mi = 0; mi < 4; ++mi)                                    \
                _Pragma("unroll")                                             \
                for (int ni = 0; ni < 3; ++ni)                                \
                    acc[mi][ni] = __builtin_amdgcn_mfma_f32_16x16x32_bf16(    \
                        af[mi], bv[ni], acc[mi][ni], 0, 0, 0);                \
        }                                                                     \
    } while (0)

    STAGE(As0, Bs0, 0);
    __syncthreads();                       // buf0 ready

#pragma unroll 1
    for (int t = 0; t < NT - 2; t += 2) {
        STAGE(As1, Bs1, t + 1);            // issue next-tile loads FIRST
        COMPUTE(As0, Bs0);                 // MFMA + co-resident waves hide them
        __syncthreads();
        STAGE(As0, Bs0, t + 2);
        COMPUTE(As1, Bs1);
        __syncthreads();
    }
    STAGE(As1, Bs1, NT - 1);
    COMPUTE(As0, Bs0);
    __syncthreads();
    COMPUTE(As1, Bs1);

#undef STAGE
#undef COMPUTE

    // epilogue: C/D layout col = lane&15, row = (lane>>4)*4 + j; add bias[n]
    const int crow = (lane >> 4) * 4;
    const int ccol = lane & 15;
#pragma unroll
    for (int mi = 0; mi < 4; ++mi)
#pragma unroll
        for (int ni = 0; ni < 3; ++ni) {
            const int n = n0 + wc * 48 + ni * 16 + ccol;
            const float bv = bias[n];
            float* cp = C + (size_t)(m0 + wr * 64 + mi * 16 + crow) * N_DIM + n;
#pragma unroll
            for (int j = 0; j < 4; ++j) cp[(size_t)j * N_DIM] = acc[mi][ni][j] + bv;
        }
}

// ---------------------------------------------------------------------------
extern "C" void kernel_launch(void* const* d_in, const int* in_sizes, int n_in,
                              void* d_out, int out_size, void* d_ws, size_t ws_size,
                              hipStream_t stream) {
    const float* x      = (const float*)d_in[0];  // (4096, 512, 3)
    const float* weight = (const float*)d_in[1];  // (512, 512)
    const float* action = (const float*)d_in[2];  // (512, 512, 8)
    const float* e0     = (const float*)d_in[3];  // (512, 1)
    float* out = (float*)d_out;                   // (4096, 512, 3)

    unsigned short* Bw = (unsigned short*)d_ws;                 // 4.7 MB
    unsigned short* Ap = Bw + (size_t)N_DIM * K_DIM;            // 12.6 MB
    float* bias = (float*)(Ap + (size_t)B_DIM * K_DIM);         // 1536 f32

    hipLaunchKernelGGL(prep, dim3(2048), dim3(512), 0, stream,
                       x, weight, action, e0, Ap, Bw, bias);
    hipLaunchKernelGGL(gemm_bf16, dim3(512), dim3(256), 0, stream,
                       Ap, Bw, bias, out);
}

// Round 10
// 49.578 us; speedup vs baseline: 7.2178x; 1.1991x over previous
//
#include <hip/hip_runtime.h>
#include <hip/hip_bf16.h>

// ---------------------------------------------------------------------------
// PGAConjugateLinear as bf16 MFMA GEMM + bias.
//   out[b, n=o*3+p] = sum_{k=i*3+r} A[b][k] * Bw[n][k]  +  bias[n]
// GEMM: M=4096, N=1536, K=1536. Tile 128x192, BK=64, grid 32x8 = 256 blocks
// = EXACTLY 1/CU (balanced; schedule hides latency, not TLP). 8 waves (2x4),
// each 64x48 (acc[4][3] = 48 VGPR).
// 8-phase-style schedule (guide T3+T4+T5, m201 template adapted):
//   per K-tile, 2 phases; each phase =
//     {7x ds_read frag -> stage-issue -> [vmcnt(5), phase 2 only] -> barrier
//      -> lgkmcnt(0)+sched_barrier(0) -> setprio(1) 12x MFMA setprio(0)
//      -> barrier}
// 3 LDS buffers (40 KB each, 120 KB total), depth-2 prefetch; 5 uniform
// global_load_lds per thread per tile -> vmcnt(5) == "tile t+1 complete,
// t+2 in flight". Never drains vmcnt in-loop.
// LDS stripe-transpose layout slot=(row>>3)*64+g*8+(row&7): conflict-free
// ds_read_b128 (0 conflicts verified R6-R9) with linear gload_lds dest.
// ---------------------------------------------------------------------------

#define B_DIM 4096
#define I_DIM 512
#define O_DIM 512
#define N_DIM (O_DIM * 3)   // 1536
#define K_DIM (I_DIM * 3)   // 1536
#define BK 64
#define NT_STEPS (K_DIM / BK)   // 24 K-tiles

typedef __attribute__((ext_vector_type(8))) short bf16x8;
typedef __attribute__((ext_vector_type(4))) float f32x4;

__device__ __forceinline__ unsigned short f2bf(float f) {
    unsigned u = __float_as_uint(f);
    unsigned r = (u + 0x7fffu + ((u >> 16) & 1u)) >> 16;  // RNE
    return (unsigned short)r;
}

__device__ __forceinline__ void gload_lds16(const void* g, void* l) {
    __builtin_amdgcn_global_load_lds(
        (const __attribute__((address_space(1))) unsigned*)g,
        (__attribute__((address_space(3))) unsigned*)l, 16, 0, 0);
}

// Cayley table for Cl(3,0,1), metric [0,1,1,1], reference blade order.
struct Cayley {
    float M[16][16][16];
    float rev[16];
    constexpr Cayley() : M{}, rev{} {
        const unsigned masks[16] = {0u, 1u, 2u, 4u, 8u, 3u, 5u, 9u, 6u, 10u,
                                    12u, 7u, 11u, 13u, 14u, 15u};
        int idx_of[16] = {};
        for (int i = 0; i < 16; ++i) idx_of[masks[i]] = i;
        const int metric[4] = {0, 1, 1, 1};
        for (int i = 0; i < 16; ++i) {
            unsigned a = masks[i];
            for (int j = 0; j < 16; ++j) {
                unsigned b = masks[j];
                int swaps = 0;
                for (int jb = 0; jb < 4; ++jb)
                    if ((b >> jb) & 1u)
                        for (int ia = jb + 1; ia < 4; ++ia)
                            if ((a >> ia) & 1u) ++swaps;
                int sign = (swaps & 1) ? -1 : 1;
                unsigned common = a & b;
                for (int g = 0; g < 4; ++g)
                    if ((common >> g) & 1u) sign *= metric[g];
                if (sign != 0) M[i][j][idx_of[a ^ b]] += (float)sign;
            }
            int grade = 0;
            for (int g = 0; g < 4; ++g) grade += (int)((a >> g) & 1u);
            rev[i] = ((grade * (grade - 1) / 2) % 2) ? -1.f : 1.f;
        }
    }
};
constexpr Cayley CAY{};

// ---------------------------------------------------------------------------
// prep: fused pack_x (blocks 0..1535) + build_w/bias (blocks 1536..2047).
// ---------------------------------------------------------------------------
__global__ __launch_bounds__(512) void prep(const float* __restrict__ x,
                                            const float* __restrict__ weight,
                                            const float* __restrict__ action,
                                            const float* __restrict__ e0,
                                            unsigned short* __restrict__ A,
                                            unsigned short* __restrict__ Bw,
                                            float* __restrict__ bias) {
    const int bid = blockIdx.x;
    const int tid = threadIdx.x;

    if (bid < 1536) {
        // ---- pack: A = bf16(x), flat cast (k=i*3+r is exactly x's layout)
        const size_t t = (size_t)bid * 512 + tid;
        const float4* xp = (const float4*)(x + t * 8);
        const float4 v0 = xp[0], v1 = xp[1];
        const float xs[8] = {v0.x, v0.y, v0.z, v0.w, v1.x, v1.y, v1.z, v1.w};
        unsigned short ov[8];
#pragma unroll
        for (int q = 0; q < 8; ++q) ov[q] = f2bf(xs[q]);
        *(uint4*)(A + t * 8) = *(const uint4*)ov;   // 16B store
        return;
    }

    // ---- build: one block per o, one thread per i.
    const int o = bid - 1536;
    const int i = tid;
    const int t = o * I_DIM + i;
    const int wave = tid >> 6, lane = tid & 63;
    __shared__ float red[8][3];

    constexpr int AB[8] = {0, 5, 6, 7, 8, 9, 10, 15};
    constexpr int PB[3] = {11, 12, 13};
    constexpr int RB[4] = {11, 12, 13, 14};

    float a[8];
    const float* ap = action + (size_t)t * 8;
#pragma unroll
    for (int j = 0; j < 8; ++j) a[j] = ap[j];

    float kv[16], kr[16];
#pragma unroll
    for (int j = 0; j < 16; ++j) { kv[j] = 0.f; kr[j] = 0.f; }
#pragma unroll
    for (int j = 0; j < 8; ++j) {
        kv[AB[j]] = a[j];
        kr[AB[j]] = a[j] * CAY.rev[AB[j]];
    }

    float Am[3][16];
#pragma unroll
    for (int pp = 0; pp < 3; ++pp)
#pragma unroll
        for (int q = 0; q < 16; ++q) {
            float s = 0.f;
#pragma unroll
            for (int tt = 0; tt < 16; ++tt) s += CAY.M[q][PB[pp]][tt] * kr[tt];
            Am[pp][q] = s;
        }

    float Bm[16][4];
#pragma unroll
    for (int q = 0; q < 16; ++q)
#pragma unroll
        for (int rr = 0; rr < 4; ++rr) {
            float s = 0.f;
#pragma unroll
            for (int m = 0; m < 16; ++m) s += CAY.M[m][q][RB[rr]] * kv[m];
            Bm[q][rr] = s;
        }

    const float w = weight[t];
    const float e0i = e0[i];
    float sb[3];
#pragma unroll
    for (int pp = 0; pp < 3; ++pp) {
        float r0 = 0.f, r1 = 0.f, r2 = 0.f, r3 = 0.f;
#pragma unroll
        for (int q = 0; q < 16; ++q) {
            r0 += Am[pp][q] * Bm[q][0];
            r1 += Am[pp][q] * Bm[q][1];
            r2 += Am[pp][q] * Bm[q][2];
            r3 += Am[pp][q] * Bm[q][3];
        }
        unsigned short* bp = Bw + (size_t)(o * 3 + pp) * K_DIM + i * 3;
        bp[0] = f2bf(w * r0);
        bp[1] = f2bf(w * r1);
        bp[2] = f2bf(w * r2);
        sb[pp] = w * r3 * e0i;
    }

#pragma unroll
    for (int off = 32; off; off >>= 1) {
#pragma unroll
        for (int pp = 0; pp < 3; ++pp) sb[pp] += __shfl_down(sb[pp], off, 64);
    }
    if (lane == 0) {
#pragma unroll
        for (int pp = 0; pp < 3; ++pp) red[wave][pp] = sb[pp];
    }
    __syncthreads();
    if (tid == 0) {
#pragma unroll
        for (int pp = 0; pp < 3; ++pp) {
            float s = 0.f;
#pragma unroll
            for (int wv = 0; wv < 8; ++wv) s += red[wv][pp];
            bias[o * 3 + pp] = s;
        }
    }
}

// ---------------------------------------------------------------------------
// gemm: C[m][n] = sum_k A[m][k]*Bw[n][k] + bias[n].
// Buffer i occupies LDS shorts [i*20480, i*20480+20480): A tile = first 8192
// shorts (1024 16B slots), B tile = next 12288 shorts (1536 slots).
// ---------------------------------------------------------------------------
__global__ __launch_bounds__(512, 2) void gemm_bf16(
        const unsigned short* __restrict__ A,
        const unsigned short* __restrict__ Bw,
        const float* __restrict__ bias,
        float* __restrict__ C) {
    __shared__ unsigned short LDS_[3 * 20480];   // 120 KB

    const int tid = threadIdx.x;
    const int wave = tid >> 6, lane = tid & 63;

    // nt = bid&7: each XCD owns one 192-wide B panel (590 KB, L2-resident).
    const int bid = blockIdx.x;
    const int nt = bid & 7, mt = bid >> 3;
    const int m0 = mt * 128, n0 = nt * 192;
    const int wr = wave >> 2, wc = wave & 3;     // 2x4 wave grid, 64x48 each

    // staging sources: slot s holds global (row=(s>>6)*8+(s&7), g=(s>>3)&7).
    // Thread stages A slots {tid, tid+512}, B slots {tid, tid+512, tid+1024}:
    // 5 loads/thread/tile, uniform across all waves (vmcnt math depends on it).
    const int sRow = ((tid >> 6) * 8) + (tid & 7);
    const int sG = (tid >> 3) & 7;
    const unsigned short* aS0 = A + (size_t)(m0 + sRow) * K_DIM + sG * 8;
    const unsigned short* aS1 = aS0 + (size_t)64 * K_DIM;    // slot+512 = row+64
    const unsigned short* bS0 = Bw + (size_t)(n0 + sRow) * K_DIM + sG * 8;
    const unsigned short* bS1 = bS0 + (size_t)64 * K_DIM;
    const unsigned short* bS2 = bS0 + (size_t)128 * K_DIM;

    // fragment read offsets (shorts): slot(r,g)*8, g = kh*4 + (lane>>4)
    const int frow = lane & 15;
    const int gl = lane >> 4;
    int aro[2][4], bro[2][3];
#pragma unroll
    for (int kh = 0; kh < 2; ++kh) {
        const int g = kh * 4 + gl;
#pragma unroll
        for (int mi = 0; mi < 4; ++mi) {
            const int r = wr * 64 + mi * 16 + frow;
            aro[kh][mi] = (((r >> 3) * 64) + g * 8 + (r & 7)) * 8;
        }
#pragma unroll
        for (int ni = 0; ni < 3; ++ni) {
            const int r = wc * 48 + ni * 16 + frow;
            bro[kh][ni] = (((r >> 3) * 64) + g * 8 + (r & 7)) * 8;
        }
    }

    f32x4 acc[4][3] = {};

    // stage-issue halves: SA = A seg0+seg1 + B seg0 (3 loads), SB = B seg1+seg2.
#define SA(BUF, T)                                                            \
    do {                                                                      \
        gload_lds16(aS0 + (size_t)(T) * BK, LDS_ + (BUF) * 20480 + tid * 8);  \
        gload_lds16(aS1 + (size_t)(T) * BK,                                   \
                    LDS_ + (BUF) * 20480 + (tid + 512) * 8);                  \
        gload_lds16(bS0 + (size_t)(T) * BK,                                   \
                    LDS_ + (BUF) * 20480 + 8192 + tid * 8);                   \
    } while (0)
#define SB(BUF, T)                                                            \
    do {                                                                      \
        gload_lds16(bS1 + (size_t)(T) * BK,                                   \
                    LDS_ + (BUF) * 20480 + 8192 + (tid + 512) * 8);           \
        gload_lds16(bS2 + (size_t)(T) * BK,                                   \
                    LDS_ + (BUF) * 20480 + 8192 + (tid + 1024) * 8);          \
    } while (0)

    // one phase: frag reads -> stage issue -> [vmcnt] -> barrier ->
    // lgkmcnt(0)+sched_barrier (rule 18) -> setprio(1) 12 MFMA setprio(0)
    // -> barrier.
#define PHASE(BUF, KH, STAGECODE, WAITCODE)                                   \
    do {                                                                      \
        const unsigned short* _ba = LDS_ + (BUF) * 20480;                     \
        const unsigned short* _bb = _ba + 8192;                               \
        bf16x8 af[4], bv[3];                                                  \
        _Pragma("unroll")                                                     \
        for (int mi = 0; mi < 4; ++mi)                                        \
            af[mi] = *(const bf16x8*)&_ba[aro[KH][mi]];                       \
        _Pragma("unroll")                                                     \
        for (int ni = 0; ni < 3; ++ni)                                        \
            bv[ni] = *(const bf16x8*)&_bb[bro[KH][ni]];                       \
        STAGECODE;                                                            \
        WAITCODE;                                                             \
        __builtin_amdgcn_s_barrier();                                         \
        asm volatile("s_waitcnt lgkmcnt(0)" ::: "memory");                    \
        __builtin_amdgcn_sched_barrier(0);                                    \
        __builtin_amdgcn_s_setprio(1);                                        \
        _Pragma("unroll")                                                     \
        for (int mi = 0; mi < 4; ++mi)                                        \
            _Pragma("unroll")                                                 \
            for (int ni = 0; ni < 3; ++ni)                                    \
                acc[mi][ni] = __builtin_amdgcn_mfma_f32_16x16x32_bf16(        \
                    af[mi], bv[ni], acc[mi][ni], 0, 0, 0);                    \
        __builtin_amdgcn_s_setprio(0);                                        \
        __builtin_amdgcn_s_barrier();                                         \
    } while (0)

#define VM5 asm volatile("s_waitcnt vmcnt(5)" ::: "memory")
#define VM0 asm volatile("s_waitcnt vmcnt(0)" ::: "memory")
#define NOPW (void)0

    // K-tile t: phase1 {reads buf[t%3] kh0, stages SA of tile t+2},
    //           phase2 {kh1, stages SB of t+2, vmcnt(5) -> tile t+1 done}.
#define TILE(CUR, N2, T)                                                      \
    PHASE(CUR, 0, SA(N2, (T) + 2), NOPW);                                     \
    PHASE(CUR, 1, SB(N2, (T) + 2), VM5)

    // prologue: stage tiles 0 and 1; publish tile 0.
    SA(0, 0); SB(0, 0);
    SA(1, 1); SB(1, 1);
    VM5;                                  // tile-0 loads complete
    __builtin_amdgcn_s_barrier();

#pragma unroll 1
    for (int v = 0; v < 7; ++v) {         // tiles t = 3v .. 3v+2 (0..20)
        TILE(0, 2, 3 * v);
        TILE(1, 0, 3 * v + 1);
        TILE(2, 1, 3 * v + 2);
    }
    TILE(0, 2, 21);                       // t=21: stages tile 23 into buf2
    PHASE(1, 0, NOPW, NOPW);              // t=22 (buf1), nothing left to stage
    PHASE(1, 1, NOPW, VM0);               //   drain: tile-23 loads complete
    PHASE(2, 0, NOPW, NOPW);              // t=23 (buf2)
    PHASE(2, 1, NOPW, NOPW);

#undef TILE
#undef PHASE
#undef SA
#undef SB
#undef VM5
#undef VM0
#undef NOPW

    // epilogue: C/D layout col = lane&15, row = (lane>>4)*4 + j; add bias[n]
    const int crow = (lane >> 4) * 4;
    const int ccol = lane & 15;
#pragma unroll
    for (int mi = 0; mi < 4; ++mi)
#pragma unroll
        for (int ni = 0; ni < 3; ++ni) {
            const int n = n0 + wc * 48 + ni * 16 + ccol;
            const float bv = bias[n];
            float* cp = C + (size_t)(m0 + wr * 64 + mi * 16 + crow) * N_DIM + n;
#pragma unroll
            for (int j = 0; j < 4; ++j) cp[(size_t)j * N_DIM] = acc[mi][ni][j] + bv;
        }
}

// ---------------------------------------------------------------------------
extern "C" void kernel_launch(void* const* d_in, const int* in_sizes, int n_in,
                              void* d_out, int out_size, void* d_ws, size_t ws_size,
                              hipStream_t stream) {
    const float* x      = (const float*)d_in[0];  // (4096, 512, 3)
    const float* weight = (const float*)d_in[1];  // (512, 512)
    const float* action = (const float*)d_in[2];  // (512, 512, 8)
    const float* e0     = (const float*)d_in[3];  // (512, 1)
    float* out = (float*)d_out;                   // (4096, 512, 3)

    unsigned short* Bw = (unsigned short*)d_ws;                 // 4.7 MB
    unsigned short* Ap = Bw + (size_t)N_DIM * K_DIM;            // 12.6 MB
    float* bias = (float*)(Ap + (size_t)B_DIM * K_DIM);         // 1536 f32

    hipLaunchKernelGGL(prep, dim3(2048), dim3(512), 0, stream,
                       x, weight, action, e0, Ap, Bw, bias);
    hipLaunchKernelGGL(gemm_bf16, dim3(256), dim3(512), 0, stream,
                       Ap, Bw, bias, out);
}